// Round 21
// baseline (27.361 us; speedup 1.0000x reference)
//
#include <hip/hip_runtime.h>
#include <hip/hip_bf16.h>

#define N_      2048
#define TWO_N   4096
#define DFEAT   128
#define SCALE   2.0f                   // 1 / TEMPERATURE
#define BROWS   128                    // rows per block  (4 waves x 32)
#define BCOLS   64                     // cols per block (LDS-staged panel)
#define NT      (BCOLS / 16)           // 4 column-tiles per panel
#define LDSTR   132                    // shorts per col (264 B): conflict-free quads
#define SC_L2E  2.8853900817779268f    // SCALE * log2(e): exp(2x) = exp2(x*SC_L2E)

typedef __attribute__((ext_vector_type(8))) short bf16x8;
typedef __attribute__((ext_vector_type(4))) float f32x4;

// ---------------------------------------------------------------------------
// Kernel 1 (fused prep) — byte-identical to R20 (zeroes accS/accP/out[0]).
// ---------------------------------------------------------------------------
__global__ __launch_bounds__(256) void k_prep(const float* __restrict__ a,
                                              const float* __restrict__ p,
                                              const float* __restrict__ ng,
                                              __hip_bfloat16* __restrict__ zn16,
                                              float* __restrict__ dvec,
                                              float* __restrict__ accS,
                                              float* __restrict__ accP,
                                              float* __restrict__ out) {
  const int wave = threadIdx.x >> 6;
  const int lane = threadIdx.x & 63;
  const int row  = blockIdx.x * 4 + wave;   // 0..4095

  if (threadIdx.x < 4)        accS[blockIdx.x * 4 + threadIdx.x] = 0.0f;
  else if (threadIdx.x < 6)   accP[blockIdx.x * 2 + threadIdx.x - 4] = 0.0f;
  if (blockIdx.x == 0 && threadIdx.x == 6) out[0] = 0.0f;

  if (row < N_) {
    float2 u = ((const float2*)(a  + (size_t)row * DFEAT))[lane];
    float2 w = ((const float2*)(ng + (size_t)row * DFEAT))[lane];
    float saa = u.x * u.x + u.y * u.y;
    float snn = w.x * w.x + w.y * w.y;
    float san = u.x * w.x + u.y * w.y;
#pragma unroll
    for (int m = 1; m < 64; m <<= 1) {
      saa += __shfl_xor(saa, m);
      snn += __shfl_xor(snn, m);
      san += __shfl_xor(san, m);
    }
    float na = fmaxf(sqrtf(saa), 1e-8f);
    float rn = 1.0f / na;
    __hip_bfloat162 h;
    h.x = __float2bfloat16(u.x * rn);
    h.y = __float2bfloat16(u.y * rn);
    ((__hip_bfloat162*)zn16)[row * (DFEAT / 2) + lane] = h;
    if (lane == 0)
      dvec[row] = SCALE * san / (na * fmaxf(sqrtf(snn), 1e-8f));
  } else {
    float2 v = ((const float2*)(p + (size_t)(row - N_) * DFEAT))[lane];
    float ss = v.x * v.x + v.y * v.y;
#pragma unroll
    for (int m = 1; m < 64; m <<= 1) ss += __shfl_xor(ss, m);
    float rn = 1.0f / fmaxf(sqrtf(ss), 1e-8f);
    __hip_bfloat162 h;
    h.x = __float2bfloat16(v.x * rn);
    h.y = __float2bfloat16(v.y * rn);
    ((__hip_bfloat162*)zn16)[row * (DFEAT / 2) + lane] = h;
  }
}

// ---------------------------------------------------------------------------
// Kernel 2 (R20 body at BCOLS=64 for 100% occupancy):
//   grid 32x64 = 2048 blocks, 256 thr (4 waves). LDS 16.9 KB -> 8 blocks/CU
//   = 32 waves/CU (was 4 blocks / 50%). Staging traffic unchanged (32 MB).
//   Block classes for 128-row x 64-col tiles (col chunk index doubled):
//     DIAG   by==2bx or 2bx+1            : exclude c==r,   -> accS
//     PARTLO bx<16, by==2bx+32 or +33    : exclude c==r+N, -> accS
//     BOUND  bx>=16, by==2bx-32 or -31   : exclude c==r-N, split c<r-N ? P : S
//     ALLP   bx>=16, by<2bx-32           : mask-free       -> accP
//     GENS   otherwise                   : mask-free       -> accS
// ---------------------------------------------------------------------------
__global__ __launch_bounds__(256) void k_simsum(const __hip_bfloat16* __restrict__ zn16,
                                                float* __restrict__ accS,
                                                float* __restrict__ accP) {
  __shared__ __align__(16) short Bp[BCOLS * LDSTR];   // 16896 B

  const int bx = blockIdx.x, by = blockIdx.y;
  const int wave = threadIdx.x >> 6;
  const int lane = threadIdx.x & 63;
  const int lr   = lane & 15;
  const int kg   = lane >> 4;
  const int rows_base = bx * BROWS + wave * 32;
  const int cb0 = by * BCOLS;
  const short* zs = (const short*)zn16;

  const bool hi = (bx >= 16);
  const int cls = (by == 2*bx || by == 2*bx + 1) ? 0                    // DIAG
                : (!hi && (by == 2*bx + 32 || by == 2*bx + 33)) ? 1     // PARTLO
                : (hi && (by == 2*bx - 32 || by == 2*bx - 31)) ? 2      // BOUND
                : (hi && by < 2*bx - 32) ? 3                            // ALLP
                : 4;                                                    // GENS

  // A fragments: two 16-row tiles (gathered once)
  bf16x8 a0[4], a1[4];
#pragma unroll
  for (int kk = 0; kk < 4; ++kk) {
    a0[kk] = *(const bf16x8*)(zs + (size_t)(rows_base + lr) * DFEAT + kk * 32 + kg * 8);
    a1[kk] = *(const bf16x8*)(zs + (size_t)(rows_base + 16 + lr) * DFEAT + kk * 32 + kg * 8);
  }

  // stage B panel: 64 cols x 256 B = 1024 16-B chunks, 256 thr -> 4 passes
#pragma unroll
  for (int it = 0; it < 4; ++it) {
    const int g   = it * 256 + threadIdx.x;
    const int col = g >> 4;
    const int q   = g & 15;
    bf16x8 v = *(const bf16x8*)(zs + (size_t)(cb0 + col) * DFEAT + q * 8);
    *(bf16x8*)(&Bp[col * LDSTR + q * 8]) = v;
  }
  __syncthreads();

  int rrow[2][4], excl[2][4];
#pragma unroll
  for (int t = 0; t < 2; ++t)
#pragma unroll
    for (int j = 0; j < 4; ++j) {
      rrow[t][j] = rows_base + t * 16 + kg * 4 + j;
      excl[t][j] = (cls == 0) ? rrow[t][j]
                 : (cls == 1) ? rrow[t][j] + N_
                 : (cls == 2) ? rrow[t][j] - N_ : -1;
    }

  float acc1v[2][4] = {{0.f,0.f,0.f,0.f},{0.f,0.f,0.f,0.f}};  // primary (S or P)
  float acc2v[2][4] = {{0.f,0.f,0.f,0.f},{0.f,0.f,0.f,0.f}};  // BOUND: prefix P

  // 2-stage register pipeline on B fragments
  bf16x8 bcur[4], bnxt[4];
#pragma unroll
  for (int kk = 0; kk < 4; ++kk)
    bcur[kk] = *(const bf16x8*)(&Bp[lr * LDSTR + kk * 32 + kg * 8]);

#pragma unroll 2
  for (int ct = 0; ct < NT; ++ct) {
    const int ctn = (ct + 1 < NT) ? (ct + 1) : ct;
#pragma unroll
    for (int kk = 0; kk < 4; ++kk)
      bnxt[kk] = *(const bf16x8*)(&Bp[(ctn * 16 + lr) * LDSTR + kk * 32 + kg * 8]);

    f32x4 acc0 = {0.f, 0.f, 0.f, 0.f};
    f32x4 acc1 = {0.f, 0.f, 0.f, 0.f};
#pragma unroll
    for (int kk = 0; kk < 4; ++kk) {
      acc0 = __builtin_amdgcn_mfma_f32_16x16x32_bf16(a0[kk], bcur[kk], acc0, 0, 0, 0);
      acc1 = __builtin_amdgcn_mfma_f32_16x16x32_bf16(a1[kk], bcur[kk], acc1, 0, 0, 0);
    }

    const int c = cb0 + ct * 16 + lr;
    if (cls >= 3) {
#pragma unroll
      for (int j = 0; j < 4; ++j) {
        acc1v[0][j] += __builtin_amdgcn_exp2f(acc0[j] * SC_L2E);
        acc1v[1][j] += __builtin_amdgcn_exp2f(acc1[j] * SC_L2E);
      }
    } else if (cls == 2) {
#pragma unroll
      for (int j = 0; j < 4; ++j) {
        float e0 = __builtin_amdgcn_exp2f(acc0[j] * SC_L2E);
        e0 = (c == excl[0][j]) ? 0.0f : e0;
        if (c < excl[0][j]) acc2v[0][j] += e0; else acc1v[0][j] += e0;
        float e1 = __builtin_amdgcn_exp2f(acc1[j] * SC_L2E);
        e1 = (c == excl[1][j]) ? 0.0f : e1;
        if (c < excl[1][j]) acc2v[1][j] += e1; else acc1v[1][j] += e1;
      }
    } else {
#pragma unroll
      for (int j = 0; j < 4; ++j) {
        float e0 = __builtin_amdgcn_exp2f(acc0[j] * SC_L2E);
        acc1v[0][j] += (c == excl[0][j]) ? 0.0f : e0;
        float e1 = __builtin_amdgcn_exp2f(acc1[j] * SC_L2E);
        acc1v[1][j] += (c == excl[1][j]) ? 0.0f : e1;
      }
    }

#pragma unroll
    for (int kk = 0; kk < 4; ++kk) bcur[kk] = bnxt[kk];
  }

  // flush: reduce across the 16 lr lanes, one atomic per row per target
#pragma unroll
  for (int t = 0; t < 2; ++t)
#pragma unroll
    for (int j = 0; j < 4; ++j) {
      float v1 = acc1v[t][j], v2 = acc2v[t][j];
#pragma unroll
      for (int m = 1; m < 16; m <<= 1) {
        v1 += __shfl_xor(v1, m);
        if (cls == 2) v2 += __shfl_xor(v2, m);
      }
      if (lr == 0) {
        const int r = rrow[t][j];
        if (cls == 3)      atomicAdd(&accP[r - N_], v1);
        else               atomicAdd(&accS[r], v1);
        if (cls == 2)      atomicAdd(&accP[r - N_], v2);
      }
    }
}

// ---------------------------------------------------------------------------
// Kernel 3 (WIDE finalize) — byte-identical to R20: 16 blocks x 256 thr.
// ---------------------------------------------------------------------------
__global__ __launch_bounds__(256) void k_final(const float* __restrict__ dvec,
                                               const float* __restrict__ accS,
                                               const float* __restrict__ accP,
                                               float* __restrict__ out) {
  __shared__ float red[4];
  __shared__ float DsumSh;
  const int tid  = threadIdx.x;
  const int wave = tid >> 6, lane = tid & 63;
  const int r    = blockIdx.x * 256 + tid;   // 0..4095

  if (blockIdx.x == 15) {
    float s = 0.f;
#pragma unroll
    for (int k = 0; k < 8; ++k) s += __expf(dvec[tid + k * 256]);
#pragma unroll
    for (int m = 1; m < 64; m <<= 1) s += __shfl_xor(s, m);
    if (lane == 0) red[wave] = s;
    __syncthreads();
    if (tid == 0) DsumSh = red[0] + red[1] + red[2] + red[3];
    __syncthreads();
  }

  const float S = accS[r];
  float term;
  if (r < N_) {
    const float dv = dvec[r];
    term = __logf(2.0f * __expf(dv) + S) - dv;
  } else {
    const int i = r - N_;
    const float extra = (i < N_ - 1) ? accP[i + 1] : DsumSh;
    const float dv = dvec[i];
    term = __logf(__expf(dv) + S + extra) - dv;
  }

#pragma unroll
  for (int m = 1; m < 64; m <<= 1) term += __shfl_xor(term, m);
  if (lane == 0) red[wave] = term;
  __syncthreads();
  if (tid == 0)
    atomicAdd(out, (red[0] + red[1] + red[2] + red[3]) * (1.0f / (float)TWO_N));
}

// ---------------------------------------------------------------------------
extern "C" void kernel_launch(void* const* d_in, const int* in_sizes, int n_in,
                              void* d_out, int out_size, void* d_ws, size_t ws_size,
                              hipStream_t stream) {
  const float* a  = (const float*)d_in[0];
  const float* p  = (const float*)d_in[1];
  const float* ng = (const float*)d_in[2];

  char* ws = (char*)d_ws;
  __hip_bfloat16* zn16 = (__hip_bfloat16*)ws;                    // 1 MB
  float* dvec = (float*)(ws + (size_t)TWO_N * DFEAT * 2);        // 16 KB slot
  float* accS = dvec + TWO_N;                                    // 16 KB
  float* accP = accS + TWO_N;                                    // 8 KB

  k_prep<<<TWO_N / 4, 256, 0, stream>>>(a, p, ng, zn16, dvec, accS, accP,
                                        (float*)d_out);
  k_simsum<<<dim3(TWO_N / BROWS, TWO_N / BCOLS), 256, 0, stream>>>(zn16, accS, accP);
  k_final<<<16, 256, 0, stream>>>(dvec, accS, accP, (float*)d_out);
}

// Round 22
// 23.095 us; speedup vs baseline: 1.1847x; 1.1847x over previous
//
#include <hip/hip_runtime.h>
#include <hip/hip_bf16.h>

#define N_      2048
#define TWO_N   4096
#define DFEAT   128
#define SCALE   2.0f                   // 1 / TEMPERATURE
#define BROWS   128                    // rows per block  (4 waves x 32)
#define BCOLS   128                    // cols per block (LDS-staged panel)
#define NT      (BCOLS / 16)           // 8 column-tiles per panel
#define LDSTR   132                    // shorts per col (264 B): conflict-free quads
#define SC_L2E  2.8853900817779268f    // SCALE * log2(e): exp(2x) = exp2(x*SC_L2E)

typedef __attribute__((ext_vector_type(8))) short bf16x8;
typedef __attribute__((ext_vector_type(4))) float f32x4;

// ---------------------------------------------------------------------------
// Kernel 1 (fused prep), 1024 blocks x 256 thr (4 waves = 4 rows per block):
//   row < N : normalize anchor row -> zn16[row], AND dvec[row] = 2*cos(a,neg)
//   row >= N: normalize pos row   -> zn16[row]
//   Zeroes accS[4096] / accP[2048] and out[0] (stream-ordered, no memset).
// ---------------------------------------------------------------------------
__global__ __launch_bounds__(256) void k_prep(const float* __restrict__ a,
                                              const float* __restrict__ p,
                                              const float* __restrict__ ng,
                                              __hip_bfloat16* __restrict__ zn16,
                                              float* __restrict__ dvec,
                                              float* __restrict__ accS,
                                              float* __restrict__ accP,
                                              float* __restrict__ out) {
  const int wave = threadIdx.x >> 6;
  const int lane = threadIdx.x & 63;
  const int row  = blockIdx.x * 4 + wave;   // 0..4095

  if (threadIdx.x < 4)        accS[blockIdx.x * 4 + threadIdx.x] = 0.0f;
  else if (threadIdx.x < 6)   accP[blockIdx.x * 2 + threadIdx.x - 4] = 0.0f;
  if (blockIdx.x == 0 && threadIdx.x == 6) out[0] = 0.0f;

  if (row < N_) {
    float2 u = ((const float2*)(a  + (size_t)row * DFEAT))[lane];
    float2 w = ((const float2*)(ng + (size_t)row * DFEAT))[lane];
    float saa = u.x * u.x + u.y * u.y;
    float snn = w.x * w.x + w.y * w.y;
    float san = u.x * w.x + u.y * w.y;
#pragma unroll
    for (int m = 1; m < 64; m <<= 1) {
      saa += __shfl_xor(saa, m);
      snn += __shfl_xor(snn, m);
      san += __shfl_xor(san, m);
    }
    float na = fmaxf(sqrtf(saa), 1e-8f);
    float rn = 1.0f / na;
    __hip_bfloat162 h;
    h.x = __float2bfloat16(u.x * rn);
    h.y = __float2bfloat16(u.y * rn);
    ((__hip_bfloat162*)zn16)[row * (DFEAT / 2) + lane] = h;
    if (lane == 0)
      dvec[row] = SCALE * san / (na * fmaxf(sqrtf(snn), 1e-8f));
  } else {
    float2 v = ((const float2*)(p + (size_t)(row - N_) * DFEAT))[lane];
    float ss = v.x * v.x + v.y * v.y;
#pragma unroll
    for (int m = 1; m < 64; m <<= 1) ss += __shfl_xor(ss, m);
    float rn = 1.0f / fmaxf(sqrtf(ss), 1e-8f);
    __hip_bfloat162 h;
    h.x = __float2bfloat16(v.x * rn);
    h.y = __float2bfloat16(v.y * rn);
    ((__hip_bfloat162*)zn16)[row * (DFEAT / 2) + lane] = h;
  }
}

// ---------------------------------------------------------------------------
// Kernel 2 (best measured config: 1024 blocks, 4 waves, NT=8, ~8 us):
//   LDS-staged B panel (padded 264-B stride, conflict-free quads), 2-stage
//   register pipeline on B fragments, two independent MFMA chains per wave,
//   block-class-specialized epilogue:
//     DIAG   by==bx           : exclude c==r,   -> accS
//     PARTLO bx<16, by==bx+16 : exclude c==r+N, -> accS
//     BOUND  bx>=16, by==bx-16: exclude c==r-N, split c<r-N ? accP : accS
//     ALLP   bx>=16, by<bx-16 : mask-free       -> accP
//     GENS   otherwise        : mask-free       -> accS
// ---------------------------------------------------------------------------
__global__ __launch_bounds__(256) void k_simsum(const __hip_bfloat16* __restrict__ zn16,
                                                float* __restrict__ accS,
                                                float* __restrict__ accP) {
  __shared__ __align__(16) short Bp[BCOLS * LDSTR];   // 33792 B

  const int bx = blockIdx.x, by = blockIdx.y;
  const int wave = threadIdx.x >> 6;
  const int lane = threadIdx.x & 63;
  const int lr   = lane & 15;
  const int kg   = lane >> 4;
  const int rows_base = bx * BROWS + wave * 32;
  const int cb0 = by * BCOLS;
  const short* zs = (const short*)zn16;

  const bool hi = (bx >= 16);
  const int cls = (by == bx) ? 0                       // DIAG
                : (!hi && by == bx + 16) ? 1           // PARTLO
                : (hi && by == bx - 16) ? 2            // BOUND
                : (hi && by < bx - 16) ? 3             // ALLP
                : 4;                                   // GENS

  // A fragments: two 16-row tiles (gathered once)
  bf16x8 a0[4], a1[4];
#pragma unroll
  for (int kk = 0; kk < 4; ++kk) {
    a0[kk] = *(const bf16x8*)(zs + (size_t)(rows_base + lr) * DFEAT + kk * 32 + kg * 8);
    a1[kk] = *(const bf16x8*)(zs + (size_t)(rows_base + 16 + lr) * DFEAT + kk * 32 + kg * 8);
  }

  // stage B panel: 128 cols x 256 B = 2048 16-B chunks, 256 thr -> 8 passes
#pragma unroll
  for (int it = 0; it < 8; ++it) {
    const int g   = it * 256 + threadIdx.x;
    const int col = g >> 4;
    const int q   = g & 15;
    bf16x8 v = *(const bf16x8*)(zs + (size_t)(cb0 + col) * DFEAT + q * 8);
    *(bf16x8*)(&Bp[col * LDSTR + q * 8]) = v;
  }
  __syncthreads();

  int rrow[2][4], excl[2][4];
#pragma unroll
  for (int t = 0; t < 2; ++t)
#pragma unroll
    for (int j = 0; j < 4; ++j) {
      rrow[t][j] = rows_base + t * 16 + kg * 4 + j;
      excl[t][j] = (cls == 0) ? rrow[t][j]
                 : (cls == 1) ? rrow[t][j] + N_
                 : (cls == 2) ? rrow[t][j] - N_ : -1;
    }

  float acc1v[2][4] = {{0.f,0.f,0.f,0.f},{0.f,0.f,0.f,0.f}};  // primary (S or P)
  float acc2v[2][4] = {{0.f,0.f,0.f,0.f},{0.f,0.f,0.f,0.f}};  // BOUND: prefix P

  // 2-stage register pipeline on B fragments
  bf16x8 bcur[4], bnxt[4];
#pragma unroll
  for (int kk = 0; kk < 4; ++kk)
    bcur[kk] = *(const bf16x8*)(&Bp[lr * LDSTR + kk * 32 + kg * 8]);

#pragma unroll 2
  for (int ct = 0; ct < NT; ++ct) {
    const int ctn = (ct + 1 < NT) ? (ct + 1) : ct;
#pragma unroll
    for (int kk = 0; kk < 4; ++kk)
      bnxt[kk] = *(const bf16x8*)(&Bp[(ctn * 16 + lr) * LDSTR + kk * 32 + kg * 8]);

    f32x4 acc0 = {0.f, 0.f, 0.f, 0.f};
    f32x4 acc1 = {0.f, 0.f, 0.f, 0.f};
#pragma unroll
    for (int kk = 0; kk < 4; ++kk) {
      acc0 = __builtin_amdgcn_mfma_f32_16x16x32_bf16(a0[kk], bcur[kk], acc0, 0, 0, 0);
      acc1 = __builtin_amdgcn_mfma_f32_16x16x32_bf16(a1[kk], bcur[kk], acc1, 0, 0, 0);
    }

    const int c = cb0 + ct * 16 + lr;
    if (cls >= 3) {
#pragma unroll
      for (int j = 0; j < 4; ++j) {
        acc1v[0][j] += __builtin_amdgcn_exp2f(acc0[j] * SC_L2E);
        acc1v[1][j] += __builtin_amdgcn_exp2f(acc1[j] * SC_L2E);
      }
    } else if (cls == 2) {
#pragma unroll
      for (int j = 0; j < 4; ++j) {
        float e0 = __builtin_amdgcn_exp2f(acc0[j] * SC_L2E);
        e0 = (c == excl[0][j]) ? 0.0f : e0;
        if (c < excl[0][j]) acc2v[0][j] += e0; else acc1v[0][j] += e0;
        float e1 = __builtin_amdgcn_exp2f(acc1[j] * SC_L2E);
        e1 = (c == excl[1][j]) ? 0.0f : e1;
        if (c < excl[1][j]) acc2v[1][j] += e1; else acc1v[1][j] += e1;
      }
    } else {
#pragma unroll
      for (int j = 0; j < 4; ++j) {
        float e0 = __builtin_amdgcn_exp2f(acc0[j] * SC_L2E);
        acc1v[0][j] += (c == excl[0][j]) ? 0.0f : e0;
        float e1 = __builtin_amdgcn_exp2f(acc1[j] * SC_L2E);
        acc1v[1][j] += (c == excl[1][j]) ? 0.0f : e1;
      }
    }

#pragma unroll
    for (int kk = 0; kk < 4; ++kk) bcur[kk] = bnxt[kk];
  }

  // flush: reduce across the 16 lr lanes, one atomic per row per target
#pragma unroll
  for (int t = 0; t < 2; ++t)
#pragma unroll
    for (int j = 0; j < 4; ++j) {
      float v1 = acc1v[t][j], v2 = acc2v[t][j];
#pragma unroll
      for (int m = 1; m < 16; m <<= 1) {
        v1 += __shfl_xor(v1, m);
        if (cls == 2) v2 += __shfl_xor(v2, m);
      }
      if (lr == 0) {
        const int r = rrow[t][j];
        if (cls == 3)      atomicAdd(&accP[r - N_], v1);
        else               atomicAdd(&accS[r], v1);
        if (cls == 2)      atomicAdd(&accP[r - N_], v2);
      }
    }
}

// ---------------------------------------------------------------------------
// Kernel 3 (WIDE finalize): 16 blocks x 256 thr, one row per thread.
//   Block partials atomicAdd into out[0] (zeroed by k_prep). Block 15
//   (owns row 2N-1) computes Dsum = sum exp(dvec) itself.
// ---------------------------------------------------------------------------
__global__ __launch_bounds__(256) void k_final(const float* __restrict__ dvec,
                                               const float* __restrict__ accS,
                                               const float* __restrict__ accP,
                                               float* __restrict__ out) {
  __shared__ float red[4];
  __shared__ float DsumSh;
  const int tid  = threadIdx.x;
  const int wave = tid >> 6, lane = tid & 63;
  const int r    = blockIdx.x * 256 + tid;   // 0..4095

  if (blockIdx.x == 15) {
    float s = 0.f;
#pragma unroll
    for (int k = 0; k < 8; ++k) s += __expf(dvec[tid + k * 256]);
#pragma unroll
    for (int m = 1; m < 64; m <<= 1) s += __shfl_xor(s, m);
    if (lane == 0) red[wave] = s;
    __syncthreads();
    if (tid == 0) DsumSh = red[0] + red[1] + red[2] + red[3];
    __syncthreads();
  }

  const float S = accS[r];
  float term;
  if (r < N_) {
    const float dv = dvec[r];
    term = __logf(2.0f * __expf(dv) + S) - dv;
  } else {
    const int i = r - N_;
    const float extra = (i < N_ - 1) ? accP[i + 1] : DsumSh;
    const float dv = dvec[i];
    term = __logf(__expf(dv) + S + extra) - dv;
  }

#pragma unroll
  for (int m = 1; m < 64; m <<= 1) term += __shfl_xor(term, m);
  if (lane == 0) red[wave] = term;
  __syncthreads();
  if (tid == 0)
    atomicAdd(out, (red[0] + red[1] + red[2] + red[3]) * (1.0f / (float)TWO_N));
}

// ---------------------------------------------------------------------------
extern "C" void kernel_launch(void* const* d_in, const int* in_sizes, int n_in,
                              void* d_out, int out_size, void* d_ws, size_t ws_size,
                              hipStream_t stream) {
  const float* a  = (const float*)d_in[0];
  const float* p  = (const float*)d_in[1];
  const float* ng = (const float*)d_in[2];

  char* ws = (char*)d_ws;
  __hip_bfloat16* zn16 = (__hip_bfloat16*)ws;                    // 1 MB
  float* dvec = (float*)(ws + (size_t)TWO_N * DFEAT * 2);        // 16 KB slot
  float* accS = dvec + TWO_N;                                    // 16 KB
  float* accP = accS + TWO_N;                                    // 8 KB

  k_prep<<<TWO_N / 4, 256, 0, stream>>>(a, p, ng, zn16, dvec, accS, accP,
                                        (float*)d_out);
  k_simsum<<<dim3(TWO_N / BROWS, TWO_N / BCOLS), 256, 0, stream>>>(zn16, accS, accP);
  k_final<<<16, 256, 0, stream>>>(dvec, accS, accP, (float*)d_out);
}